// Round 1
// baseline (346.255 us; speedup 1.0000x reference)
//
#include <hip/hip_runtime.h>
#include <cmath>

#define Bn 32768
#define Ln 256
#define Pn 1024
#define Dn 50
#define Cn 3
#define Sn 10

// ---------------- pp softmax over axis=1 (p), per (c,n) ----------------
__global__ void pp_softmax_kernel(const float* __restrict__ pres, float* __restrict__ pp) {
    int c = blockIdx.x / Sn;
    int n = blockIdx.x % Sn;
    int lane = threadIdx.x; // 64 threads
    const float* src = pres + (size_t)c * Pn * Sn + n;
    float* dst = pp + (size_t)c * Pn * Sn + n;
    float v[16];
    float mx = -1e30f;
#pragma unroll
    for (int i = 0; i < 16; ++i) { v[i] = src[(size_t)(lane + i * 64) * Sn]; mx = fmaxf(mx, v[i]); }
#pragma unroll
    for (int m = 1; m < 64; m <<= 1) mx = fmaxf(mx, __shfl_xor(mx, m, 64));
    float sum = 0.f;
#pragma unroll
    for (int i = 0; i < 16; ++i) { v[i] = __expf(v[i] - mx); sum += v[i]; }
#pragma unroll
    for (int m = 1; m < 64; m <<= 1) sum += __shfl_xor(sum, m, 64);
    float inv = 1.0f / sum;
#pragma unroll
    for (int i = 0; i < 16; ++i) dst[(size_t)(lane + i * 64) * Sn] = v[i] * inv;
}

// ---------------- ppsum[c,p] = sum_n pp[c,p,n]  (folds Wc slot-sum) ----------------
__global__ void pp_rowsum_kernel(const float* __restrict__ pp, float* __restrict__ pps) {
    int idx = blockIdx.x * blockDim.x + threadIdx.x;
    if (idx < Cn * Pn) {
        float s = 0.f;
#pragma unroll
        for (int n = 0; n < Sn; ++n) s += pp[(size_t)idx * Sn + n];
        pps[idx] = s;
    }
}

// ---------------- projection: Linear(256->50) -> InstanceNorm -> ReLU -> Linear(50->50) ----------------
// wave-per-4-rows; lane j (<50) owns output feature j. Also writes row squared-norms.
__global__ __launch_bounds__(256) void project_kernel(
    const float* __restrict__ zin,
    const float* __restrict__ W1, const float* __restrict__ b1,
    const float* __restrict__ W2, const float* __restrict__ b2,
    float* __restrict__ outp, float* __restrict__ outn, int rowsPerWave)
{
    __shared__ float w1s[Dn][Ln + 1];   // 51.4 KB, stride 257 -> <=2-way conflicts
    __shared__ float w2s[Dn][Dn + 1];   // 10.2 KB
    __shared__ float zs[4][4][Ln];      // 16 KB (per-wave, 4 rows)
    __shared__ float rs[4][4][Dn + 2];  // 3.3 KB

    int t = threadIdx.x;
    for (int idx = t; idx < Dn * Ln; idx += 256) w1s[idx >> 8][idx & (Ln - 1)] = W1[idx];
    for (int idx = t; idx < Dn * Dn; idx += 256) w2s[idx / Dn][idx % Dn] = W2[idx];
    int wave = t >> 6, lane = t & 63;
    int jj = lane < Dn ? lane : 0;
    bool act = lane < Dn;
    float rb1 = b1[jj], rb2 = b2[jj];
    __syncthreads();

    int rowBase = (blockIdx.x * 4 + wave) * rowsPerWave;
    for (int rr = 0; rr < rowsPerWave; rr += 4) {
        int row0 = rowBase + rr;
#pragma unroll
        for (int r = 0; r < 4; ++r)
#pragma unroll
            for (int i = 0; i < 4; ++i)
                zs[wave][r][lane + i * 64] = zin[(size_t)(row0 + r) * Ln + lane + i * 64];
        __syncthreads();

        float h0 = rb1, h1 = rb1, h2 = rb1, h3 = rb1;
#pragma unroll 4
        for (int k = 0; k < Ln; ++k) {
            float w = w1s[jj][k];
            h0 += zs[wave][0][k] * w;
            h1 += zs[wave][1][k] * w;
            h2 += zs[wave][2][k] * w;
            h3 += zs[wave][3][k] * w;
        }
        float hh[4] = {h0, h1, h2, h3};
#pragma unroll
        for (int r = 0; r < 4; ++r) {
            float h = hh[r];
            float s = act ? h : 0.f;
#pragma unroll
            for (int m = 1; m < 64; m <<= 1) s += __shfl_xor(s, m, 64);
            float mean = s * (1.0f / Dn);
            float dv = act ? (h - mean) : 0.f;
            float s2 = dv * dv;
#pragma unroll
            for (int m = 1; m < 64; m <<= 1) s2 += __shfl_xor(s2, m, 64);
            float var = s2 * (1.0f / Dn);
            float rv = fmaxf((h - mean) * rsqrtf(var + 1e-5f), 0.f);
            if (act) rs[wave][r][lane] = rv;
        }
        __syncthreads();

        float o0 = rb2, o1 = rb2, o2 = rb2, o3 = rb2;
#pragma unroll 2
        for (int k = 0; k < Dn; ++k) {
            float w = w2s[jj][k];
            o0 += rs[wave][0][k] * w;
            o1 += rs[wave][1][k] * w;
            o2 += rs[wave][2][k] * w;
            o3 += rs[wave][3][k] * w;
        }
        float oo[4] = {o0, o1, o2, o3};
#pragma unroll
        for (int r = 0; r < 4; ++r) {
            float o = oo[r];
            if (act) outp[(size_t)(row0 + r) * Dn + lane] = o;
            float q = act ? o * o : 0.f;
#pragma unroll
            for (int m = 1; m < 64; m <<= 1) q += __shfl_xor(q, m, 64);
            if (lane == 0) outn[row0 + r] = q;
        }
        __syncthreads();
    }
}

// ---------------- sim = log((l2+1)/(l2+eps)) + fused out2 reduction ----------------
// block: 64 rows x all 1024 protos (8 tiles of 128). thread-tile 4 rows x 8 protos.
__global__ __launch_bounds__(256) void sim_kernel(
    const float* __restrict__ xp, const float* __restrict__ xpn,
    const float* __restrict__ lp, const float* __restrict__ lpn,
    const float* __restrict__ ppsum,
    float* __restrict__ sim, float* __restrict__ out2)
{
    __shared__ float xs[64][53];
    __shared__ float ls[128][53];
    __shared__ float lns[128];
    __shared__ float pps[Cn * Pn];

    int t = threadIdx.x;
    int tx = t & 15, ty = t >> 4;
    int row0 = blockIdx.x * 64;

    for (int idx = t; idx < 64 * Dn; idx += 256) {
        int r = idx / Dn, c = idx - r * Dn;
        xs[r][c] = xp[(size_t)(row0 + r) * Dn + c];
    }
    for (int idx = t; idx < Cn * Pn; idx += 256) pps[idx] = ppsum[idx];

    float xn[4];
#pragma unroll
    for (int i = 0; i < 4; ++i) xn[i] = xpn[row0 + ty * 4 + i];

    float oacc[3][4] = {};

    for (int pt = 0; pt < Pn / 128; ++pt) {
        int p0 = pt * 128;
        __syncthreads();
        for (int idx = t; idx < 128 * Dn; idx += 256) {
            int r = idx / Dn, c = idx - r * Dn;
            ls[r][c] = lp[(size_t)(p0 + r) * Dn + c];
        }
        if (t < 128) lns[t] = lpn[p0 + t];
        __syncthreads();

        float acc[4][8];
#pragma unroll
        for (int i = 0; i < 4; ++i)
#pragma unroll
            for (int q = 0; q < 8; ++q) acc[i][q] = 0.f;

#pragma unroll 2
        for (int k = 0; k < Dn; ++k) {
            float xv[4], lv[8];
#pragma unroll
            for (int i = 0; i < 4; ++i) xv[i] = xs[ty * 4 + i][k];
#pragma unroll
            for (int g = 0; g < 2; ++g)
#pragma unroll
                for (int j = 0; j < 4; ++j) lv[g * 4 + j] = ls[g * 64 + tx * 4 + j][k];
#pragma unroll
            for (int i = 0; i < 4; ++i)
#pragma unroll
                for (int q = 0; q < 8; ++q) acc[i][q] += xv[i] * lv[q];
        }

#pragma unroll
        for (int i = 0; i < 4; ++i) {
            int row = row0 + ty * 4 + i;
#pragma unroll
            for (int g = 0; g < 2; ++g) {
                float4 sv;
#pragma unroll
                for (int j = 0; j < 4; ++j) {
                    int pl = g * 64 + tx * 4 + j;
                    float l2 = xn[i] + lns[pl] - 2.f * acc[i][g * 4 + j];
                    l2 = fmaxf(l2, 0.f);
                    float sval = __logf(__fdividef(l2 + 1.f, l2 + 1e-5f));
                    (&sv.x)[j] = sval;
                    const float* ppc = &pps[p0 + pl];
                    oacc[0][i] += sval * ppc[0];
                    oacc[1][i] += sval * ppc[Pn];
                    oacc[2][i] += sval * ppc[2 * Pn];
                }
                *reinterpret_cast<float4*>(sim + (size_t)row * Pn + p0 + g * 64 + tx * 4) = sv;
            }
        }
    }

#pragma unroll
    for (int c = 0; c < 3; ++c)
#pragma unroll
        for (int i = 0; i < 4; ++i) {
            float v = oacc[c][i];
            v += __shfl_xor(v, 1, 64);
            v += __shfl_xor(v, 2, 64);
            v += __shfl_xor(v, 4, 64);
            v += __shfl_xor(v, 8, 64);
            if (tx == 0) {
                int row = row0 + ty * 4 + i;
                out2[(size_t)row * 3 + c] = (c == 0) ? tanhf(v) : fmaxf(v, 0.f);
            }
        }
}

extern "C" void kernel_launch(void* const* d_in, const int* in_sizes, int n_in,
                              void* d_out, int out_size, void* d_ws, size_t ws_size,
                              hipStream_t stream) {
    const float* x    = (const float*)d_in[0];
    const float* prot = (const float*)d_in[2];
    const float* pres = (const float*)d_in[3];
    const float* W1   = (const float*)d_in[4];
    const float* b1   = (const float*)d_in[5];
    const float* W2   = (const float*)d_in[6];
    const float* b2   = (const float*)d_in[7];

    float* out  = (float*)d_out;
    float* out2 = out;                           // [B,3]
    float* xp   = out + (size_t)Bn * Cn;         // [B,50]
    float* sim  = xp + (size_t)Bn * Dn;          // [B,1024]
    float* pp   = sim + (size_t)Bn * Pn;         // [3,1024,10]

    float* ws    = (float*)d_ws;
    float* lpbuf = ws;                  // [1024,50]
    float* lpn   = lpbuf + Pn * Dn;     // [1024]
    float* xpn   = lpn + Pn;            // [32768]
    float* pps   = xpn + Bn;            // [3,1024]

    hipLaunchKernelGGL(pp_softmax_kernel, dim3(Cn * Sn), dim3(64), 0, stream, pres, pp);
    hipLaunchKernelGGL(pp_rowsum_kernel, dim3((Cn * Pn + 255) / 256), dim3(256), 0, stream, pp, pps);
    hipLaunchKernelGGL(project_kernel, dim3(Bn / 32), dim3(256), 0, stream,
                       x, W1, b1, W2, b2, xp, xpn, 8);
    hipLaunchKernelGGL(project_kernel, dim3(Pn / 32), dim3(256), 0, stream,
                       prot, W1, b1, W2, b2, lpbuf, lpn, 8);
    hipLaunchKernelGGL(sim_kernel, dim3(Bn / 64), dim3(256), 0, stream,
                       xp, xpn, lpbuf, lpn, pps, sim, out2);
}

// Round 4
// 325.211 us; speedup vs baseline: 1.0647x; 1.0647x over previous
//
#include <hip/hip_runtime.h>
#include <cmath>

#define Bn 32768
#define Ln 256
#define Pn 1024
#define Dn 50
#define Cn 3
#define Sn 10

typedef short bf16x8 __attribute__((ext_vector_type(8)));
typedef float f32x4 __attribute__((ext_vector_type(4)));

__device__ inline unsigned short f2bf(float f) {
    unsigned int u = __float_as_uint(f);
    unsigned int r = (u + 0x7FFFu + ((u >> 16) & 1u)) >> 16;
    return (unsigned short)r;
}

// ---------------- pp softmax over axis=1 (p), per (c,n) ----------------
__global__ void pp_softmax_kernel(const float* __restrict__ pres, float* __restrict__ pp) {
    int c = blockIdx.x / Sn;
    int n = blockIdx.x % Sn;
    int lane = threadIdx.x; // 64 threads
    const float* src = pres + (size_t)c * Pn * Sn + n;
    float* dst = pp + (size_t)c * Pn * Sn + n;
    float v[16];
    float mx = -1e30f;
#pragma unroll
    for (int i = 0; i < 16; ++i) { v[i] = src[(size_t)(lane + i * 64) * Sn]; mx = fmaxf(mx, v[i]); }
#pragma unroll
    for (int m = 1; m < 64; m <<= 1) mx = fmaxf(mx, __shfl_xor(mx, m, 64));
    float sum = 0.f;
#pragma unroll
    for (int i = 0; i < 16; ++i) { v[i] = __expf(v[i] - mx); sum += v[i]; }
#pragma unroll
    for (int m = 1; m < 64; m <<= 1) sum += __shfl_xor(sum, m, 64);
    float inv = 1.0f / sum;
#pragma unroll
    for (int i = 0; i < 16; ++i) dst[(size_t)(lane + i * 64) * Sn] = v[i] * inv;
}

__global__ void pp_rowsum_kernel(const float* __restrict__ pp, float* __restrict__ pps) {
    int idx = blockIdx.x * blockDim.x + threadIdx.x;
    if (idx < Cn * Pn) {
        float s = 0.f;
#pragma unroll
        for (int n = 0; n < Sn; ++n) s += pp[(size_t)idx * Sn + n];
        pps[idx] = s;
    }
}

// ---------------- projection: Linear(256->50) -> InstanceNorm -> ReLU -> Linear(50->50) ----------------
// 64 rows/block, 256 threads; thread (tx,ty) owns rows ty*4+i, cols tx*4+j (N padded to 64).
// Rows are wave-private (ty = wave*4 + lg), so InstanceNorm needs only the 16-lane tx shuffle.
__global__ __launch_bounds__(256) void project_kernel(
    const float* __restrict__ zin,
    const float* __restrict__ W1, const float* __restrict__ b1,
    const float* __restrict__ W2, const float* __restrict__ b2,
    float* __restrict__ outp, float* __restrict__ outn,
    unsigned short* __restrict__ outb)
{
    __shared__ float xs[64][68];   // rows x k-chunk (also reused for normalized h)
    __shared__ float w1t[64][68];  // k x col (transposed W1 chunk, cols padded to 64)
    __shared__ float w2t[52][68];  // k x col (transposed W2, k padded to 52)

    int t = threadIdx.x;
    int tx = t & 15, ty = t >> 4;
    int row0 = blockIdx.x * 64;

    for (int idx = t; idx < 52 * 64; idx += 256) {
        int j = idx & 63, k = idx >> 6;
        w2t[k][j] = (j < Dn && k < Dn) ? W2[j * Dn + k] : 0.f;
    }

    float acc[4][4] = {};
    for (int kc = 0; kc < Ln; kc += 64) {
        __syncthreads();
        for (int idx = t; idx < 64 * 64; idx += 256) {
            int kk = idx & 63, r = idx >> 6;
            xs[r][kk] = zin[(size_t)(row0 + r) * Ln + kc + kk];
        }
        for (int idx = t; idx < 64 * 64; idx += 256) {
            int j = idx & 63, kk = idx >> 6;
            w1t[kk][j] = (j < Dn) ? W1[j * Ln + kc + kk] : 0.f;
        }
        __syncthreads();
#pragma unroll 4
        for (int k4 = 0; k4 < 16; ++k4) {
            float4 xv[4], wv[4];
#pragma unroll
            for (int i = 0; i < 4; ++i) xv[i] = *(const float4*)&xs[ty * 4 + i][k4 * 4];
#pragma unroll
            for (int kk = 0; kk < 4; ++kk) wv[kk] = *(const float4*)&w1t[k4 * 4 + kk][tx * 4];
#pragma unroll
            for (int i = 0; i < 4; ++i)
#pragma unroll
                for (int kk = 0; kk < 4; ++kk)
#pragma unroll
                    for (int j = 0; j < 4; ++j)
                        acc[i][j] += (&xv[i].x)[kk] * (&wv[kk].x)[j];
        }
    }

    float rb1[4], rb2[4];
    bool valid[4];
#pragma unroll
    for (int j = 0; j < 4; ++j) {
        int c = tx * 4 + j;
        valid[j] = c < Dn;
        rb1[j] = valid[j] ? b1[c] : 0.f;
        rb2[j] = valid[j] ? b2[c] : 0.f;
    }

    __syncthreads();  // all GEMM1 LDS reads done before xs is overwritten with rs

    // instance norm + relu, write normalized values back into xs
#pragma unroll
    for (int i = 0; i < 4; ++i) {
        float h[4];
        float s = 0.f;
#pragma unroll
        for (int j = 0; j < 4; ++j) { h[j] = acc[i][j] + rb1[j]; s += h[j]; }
#pragma unroll
        for (int m = 1; m < 16; m <<= 1) s += __shfl_xor(s, m, 64);
        float mean = s * (1.0f / Dn);
        float s2 = 0.f;
#pragma unroll
        for (int j = 0; j < 4; ++j) { float dv = valid[j] ? (h[j] - mean) : 0.f; s2 += dv * dv; }
#pragma unroll
        for (int m = 1; m < 16; m <<= 1) s2 += __shfl_xor(s2, m, 64);
        float rstd = rsqrtf(s2 * (1.0f / Dn) + 1e-5f);
        float4 rv;
#pragma unroll
        for (int j = 0; j < 4; ++j)
            (&rv.x)[j] = valid[j] ? fmaxf((h[j] - mean) * rstd, 0.f) : 0.f;
        *(float4*)&xs[ty * 4 + i][tx * 4] = rv;
    }
    __syncthreads();

    float acc2[4][4] = {};
#pragma unroll 4
    for (int k4 = 0; k4 < 13; ++k4) {
        float4 xv[4], wv[4];
#pragma unroll
        for (int i = 0; i < 4; ++i) xv[i] = *(const float4*)&xs[ty * 4 + i][k4 * 4];
#pragma unroll
        for (int kk = 0; kk < 4; ++kk) wv[kk] = *(const float4*)&w2t[k4 * 4 + kk][tx * 4];
#pragma unroll
        for (int i = 0; i < 4; ++i)
#pragma unroll
            for (int kk = 0; kk < 4; ++kk)
#pragma unroll
                for (int j = 0; j < 4; ++j)
                    acc2[i][j] += (&xv[i].x)[kk] * (&wv[kk].x)[j];
    }

#pragma unroll
    for (int i = 0; i < 4; ++i) {
        int row = row0 + ty * 4 + i;
        float o[4];
        float q = 0.f;
#pragma unroll
        for (int j = 0; j < 4; ++j) {
            o[j] = acc2[i][j] + rb2[j];
            if (valid[j]) q += o[j] * o[j];
            if (valid[j]) outp[(size_t)row * Dn + tx * 4 + j] = o[j];
        }
        ushort4 ob;
        ob.x = valid[0] ? f2bf(o[0]) : 0;
        ob.y = valid[1] ? f2bf(o[1]) : 0;
        ob.z = valid[2] ? f2bf(o[2]) : 0;
        ob.w = valid[3] ? f2bf(o[3]) : 0;
        *(ushort4*)&outb[(size_t)row * 64 + tx * 4] = ob;
#pragma unroll
        for (int m = 1; m < 16; m <<= 1) q += __shfl_xor(q, m, 64);
        if (tx == 0) outn[row] = q;
    }
}

// ---------------- sim via bf16 MFMA + fused log + out1 partials ----------------
// 512 blocks x 64 rows; wave w covers protos w*256 .. +255 in 4 tiles of 64.
__global__ __launch_bounds__(256) void sim_mfma_kernel(
    const unsigned short* __restrict__ xpb, const unsigned short* __restrict__ lpb,
    const float* __restrict__ xpn, const float* __restrict__ lpn,
    const float* __restrict__ pps,
    float* __restrict__ sim, float* __restrict__ out1)
{
    int t = threadIdx.x;
    int w = t >> 6, l = t & 63;
    int lr = l & 15, lg = l >> 4;
    int row0 = blockIdx.x * 64;

    bf16x8 af[4][2];
#pragma unroll
    for (int m = 0; m < 4; ++m)
#pragma unroll
        for (int ks = 0; ks < 2; ++ks)
            af[m][ks] = *(const bf16x8*)&xpb[(size_t)(row0 + m * 16 + lr) * 64 + ks * 32 + lg * 8];

    float xnr[4][4];
#pragma unroll
    for (int m = 0; m < 4; ++m)
#pragma unroll
        for (int i = 0; i < 4; ++i)
            xnr[m][i] = xpn[row0 + m * 16 + lg * 4 + i];

    float oacc[4][4][3] = {};  // [m][i][c]

    for (int pt = 0; pt < 4; ++pt) {
#pragma unroll
        for (int n = 0; n < 4; ++n) {
            int pc = w * 256 + pt * 64 + n * 16;
            bf16x8 bfr[2];
#pragma unroll
            for (int ks = 0; ks < 2; ++ks)
                bfr[ks] = *(const bf16x8*)&lpb[(size_t)(pc + lr) * 64 + ks * 32 + lg * 8];
            f32x4 acc[4];
#pragma unroll
            for (int m = 0; m < 4; ++m) { f32x4 z = {0.f, 0.f, 0.f, 0.f}; acc[m] = z; }
#pragma unroll
            for (int ks = 0; ks < 2; ++ks)
#pragma unroll
                for (int m = 0; m < 4; ++m)
                    acc[m] = __builtin_amdgcn_mfma_f32_16x16x32_bf16(af[m][ks], bfr[ks], acc[m], 0, 0, 0);

            float ln = lpn[pc + lr];
            float pr0 = pps[pc + lr];
            float pr1 = pps[Pn + pc + lr];
            float pr2 = pps[2 * Pn + pc + lr];
#pragma unroll
            for (int m = 0; m < 4; ++m)
#pragma unroll
                for (int i = 0; i < 4; ++i) {
                    float l2 = xnr[m][i] + ln - 2.f * acc[m][i];
                    l2 = fmaxf(l2, 0.f);
                    float s = __logf(__fdividef(l2 + 1.f, l2 + 1e-5f));
                    sim[(size_t)(row0 + m * 16 + lg * 4 + i) * Pn + pc + lr] = s;
                    oacc[m][i][0] += s * pr0;
                    oacc[m][i][1] += s * pr1;
                    oacc[m][i][2] += s * pr2;
                }
        }
    }

#pragma unroll
    for (int m = 0; m < 4; ++m)
#pragma unroll
        for (int i = 0; i < 4; ++i)
#pragma unroll
            for (int c = 0; c < 3; ++c) {
                float v = oacc[m][i][c];
                v += __shfl_xor(v, 1, 64);
                v += __shfl_xor(v, 2, 64);
                v += __shfl_xor(v, 4, 64);
                v += __shfl_xor(v, 8, 64);
                if (lr == 0)
                    atomicAdd(&out1[(size_t)(row0 + m * 16 + lg * 4 + i) * Cn + c], v);
            }
}

__global__ void finalize_kernel(const float* __restrict__ o1, float* __restrict__ out2) {
    int i = blockIdx.x * 256 + threadIdx.x;
    if (i < Bn * Cn) {
        float v = o1[i];
        int c = i - (i / Cn) * Cn;
        out2[i] = (c == 0) ? tanhf(v) : fmaxf(v, 0.f);
    }
}

extern "C" void kernel_launch(void* const* d_in, const int* in_sizes, int n_in,
                              void* d_out, int out_size, void* d_ws, size_t ws_size,
                              hipStream_t stream) {
    const float* x    = (const float*)d_in[0];
    const float* prot = (const float*)d_in[2];
    const float* pres = (const float*)d_in[3];
    const float* W1   = (const float*)d_in[4];
    const float* b1   = (const float*)d_in[5];
    const float* W2   = (const float*)d_in[6];
    const float* b2   = (const float*)d_in[7];

    float* out  = (float*)d_out;
    float* out2 = out;                           // [B,3]
    float* xp   = out + (size_t)Bn * Cn;         // [B,50]
    float* sim  = xp + (size_t)Bn * Dn;          // [B,1024]
    float* pp   = sim + (size_t)Bn * Pn;         // [3,1024,10]

    float* ws     = (float*)d_ws;
    float* out1ws = ws;                          // [B,3]
    float* xpn    = out1ws + (size_t)Bn * Cn;    // [B]
    float* lpn    = xpn + Bn;                    // [P]
    float* pps    = lpn + Pn;                    // [3,P]
    float* lpf    = pps + Cn * Pn;               // [P,50] dummy fp32 proto projection
    unsigned short* xpb = (unsigned short*)(lpf + Pn * Dn);  // [B,64] bf16
    unsigned short* lpb = xpb + (size_t)Bn * 64;             // [P,64] bf16

    hipMemsetAsync(out1ws, 0, (size_t)Bn * Cn * sizeof(float), stream);
    hipLaunchKernelGGL(pp_softmax_kernel, dim3(Cn * Sn), dim3(64), 0, stream, pres, pp);
    hipLaunchKernelGGL(pp_rowsum_kernel, dim3((Cn * Pn + 255) / 256), dim3(256), 0, stream, pp, pps);
    hipLaunchKernelGGL(project_kernel, dim3(Bn / 64), dim3(256), 0, stream,
                       x, W1, b1, W2, b2, xp, xpn, xpb);
    hipLaunchKernelGGL(project_kernel, dim3(Pn / 64), dim3(256), 0, stream,
                       prot, W1, b1, W2, b2, lpf, lpn, lpb);
    hipLaunchKernelGGL(sim_mfma_kernel, dim3(Bn / 64), dim3(256), 0, stream,
                       xpb, lpb, xpn, lpn, pps, sim, out1ws);
    hipLaunchKernelGGL(finalize_kernel, dim3((Bn * Cn + 255) / 256), dim3(256), 0, stream,
                       out1ws, out2);
}